// Round 22
// baseline (623.195 us; speedup 1.0000x reference)
//
#include <hip/hip_runtime.h>
#include <hip/hip_bf16.h>

#define NPIX 73728
#define CH 64
#define HH 96
#define WW 96
#define PP 256
#define CSTR 32  // counter stride in ints (128B)

typedef __attribute__((ext_vector_type(8))) short short8;
typedef __attribute__((ext_vector_type(4))) float f32x4;

__device__ __forceinline__ float wsum64(float v) {
#pragma unroll
  for (int off = 32; off > 0; off >>= 1) v += __shfl_xor(v, off, 64);
  return v;
}
__device__ __forceinline__ float wsum16(float v) {
#pragma unroll
  for (int off = 1; off < 16; off <<= 1) v += __shfl_xor(v, off, 64);
  return v;
}
__device__ __forceinline__ float gelu_f(float x) {
  return 0.5f * x * (1.0f + erff(x * 0.70710678118654752f));
}
__device__ __forceinline__ float b2f(ushort u) {
  union { unsigned int i; float f; } c;
  c.i = ((unsigned int)u) << 16;
  return c.f;
}
__device__ __forceinline__ ushort f2b(float f) {
  union { float f; unsigned int i; } c;
  c.f = f;
  unsigned int r = c.i + 0x7fff + ((c.i >> 16) & 1);
  return (ushort)(r >> 16);
}

// ------- init: xs = x, zero outputs/acc, zero padded counters -------
__global__ __launch_bounds__(256) void k_init(const float* __restrict__ x,
                                              float* __restrict__ xs,
                                              float* __restrict__ out,
                                              float* __restrict__ accb,
                                              int* __restrict__ cnt) {
  int i = blockIdx.x * 256 + threadIdx.x;
  if (i < NPIX * CH) xs[i] = x[i];
  if (i < NPIX * 66) out[i] = 0.0f;  // so | halted | pc
  if (i < NPIX) accb[i] = 0.0f;
  if (i < 9 * CSTR) cnt[i] = 0;
}

// ------- weight prep (ALL 3 matrices in one launch): fp32 [K,N] ->
// fragment-linear bf16. Element t of matrix with NT=N/16:
// j=t&7, l=(t>>3)&63, tile=t>>9; k=kt*32+((l>>4)&3)*8+j; n=nt*16+(l&15).
__device__ __forceinline__ void wprep_one(const float* W, ushort* Wp, int t,
                                          int N) {
  int j = t & 7, l = (t >> 3) & 63, tile = t >> 9;
  int NT = N >> 4;
  int kt = tile / NT, nt = tile - kt * NT;
  int k = kt * 32 + ((l >> 4) & 3) * 8 + j;
  int n = nt * 16 + (l & 15);
  Wp[t] = f2b(W[k * N + n]);
}
__global__ __launch_bounds__(256) void k_wprep_all(
    const float* __restrict__ Wu1, ushort* __restrict__ Wp1,
    const float* __restrict__ Wu2, ushort* __restrict__ Wp2,
    const float* __restrict__ Wu3, ushort* __restrict__ Wp3) {
  int t = blockIdx.x * 256 + threadIdx.x;
  if (t < 32768) {
    wprep_one(Wu1, Wp1, t, 128);
  } else if (t < 32768 + 8192) {
    wprep_one(Wu2, Wp2, t - 32768, 64);
  } else if (t < 32768 + 8192 + 4096) {
    wprep_one(Wu3, Wp3, t - 32768 - 8192, 64);
  }
}

// ---- K1: FUSED compact (blocks [0,288)) + list-driven LN/halt (rest) ----
// ln half: all of list[t-1] gets xn refresh; hp matvec (phases 2-3) only for
// pixels still active (halted==0) — just-halted pixels' hp is never read
// again. Skips are block-uniform (LDS flags) so __syncthreads stays uniform.
__global__ __launch_bounds__(256) void k_cln(
    const float* __restrict__ halted, int* __restrict__ cnt,
    int* __restrict__ lst_out, int step,
    const float* __restrict__ xs, ushort* __restrict__ xn,
    float* __restrict__ hp, const int* __restrict__ lst_in, int lslot,
    int ident,
    const float* __restrict__ g1, const float* __restrict__ b1,
    const float* __restrict__ gh, const float* __restrict__ bh,
    const float* __restrict__ Wh1, const float* __restrict__ bh1,
    const float* __restrict__ Wh2, const float* __restrict__ bh2) {
  if (blockIdx.x < NPIX / 256) {
    // ---- compaction half ----
    int p = blockIdx.x * 256 + threadIdx.x;
    bool active = (halted[p] == 0.0f);
    unsigned long long mask = __ballot(active);
    int lane = threadIdx.x & 63;
    int cw = __popcll(mask);
    int wbase = 0;
    if (lane == 0 && cw) wbase = atomicAdd(&cnt[step * CSTR], cw);
    wbase = __shfl(wbase, 0, 64);
    if (active) {
      int off = __popcll(mask & ((1ull << lane) - 1ull));
      lst_out[wbase + off] = p;
    }
    return;
  }
  // ---- LN/halt half ----
  int bid = blockIdx.x - NPIX / 256;
  int m = ident ? NPIX : cnt[lslot * CSTR];
  if (bid * 4 >= m) return;
  __shared__ float lnbuf[4][64];
  __shared__ float partials[4][4][64];  // [src wave][pixel][lane]
  __shared__ int need[4];
  int wave = threadIdx.x >> 6, lane = threadIdx.x & 63;
  int slot = bid * 4 + wave;
  bool act = slot < m;
  int sl = act ? slot : m - 1;
  int pix = ident ? sl : lst_in[sl];
  bool needhp = act && (halted[pix] == 0.0f);  // wave-uniform scalar
  if (lane == 0) need[wave] = needhp ? 1 : 0;
  if (act) {
    float x = xs[(size_t)pix * CH + lane];
    float mean = wsum64(x) * (1.0f / 64.0f);
    float d = x - mean;
    float var = wsum64(d * d) * (1.0f / 64.0f);
    float rstd = rsqrtf(var + 1e-5f);
    float nrm = d * rstd;
    xn[(size_t)pix * CH + lane] = f2b(nrm * g1[lane] + b1[lane]);
    lnbuf[wave][lane] = nrm * gh[lane] + bh[lane];
  } else {
    lnbuf[wave][lane] = 0.0f;
  }
  __syncthreads();
  if (!(need[0] | need[1] | need[2] | need[3])) return;  // block-uniform

  float start = (wave == 0) ? bh1[lane] : 0.0f;
  float p0 = start, p1 = start, p2 = start, p3 = start;
  int i0 = wave * 16;
#pragma unroll 4
  for (int i = i0; i < i0 + 16; ++i) {
    float w = Wh1[i * 64 + lane];
    p0 = fmaf(lnbuf[0][i], w, p0);
    p1 = fmaf(lnbuf[1][i], w, p1);
    p2 = fmaf(lnbuf[2][i], w, p2);
    p3 = fmaf(lnbuf[3][i], w, p3);
  }
  partials[wave][0][lane] = p0;
  partials[wave][1][lane] = p1;
  partials[wave][2][lane] = p2;
  partials[wave][3][lane] = p3;
  __syncthreads();

  if (need[wave]) {
    float s = (partials[0][wave][lane] + partials[1][wave][lane]) +
              (partials[2][wave][lane] + partials[3][wave][lane]);
    float acc = gelu_f(s);
    float c = wsum64(acc * Wh2[lane]);
    if (lane == 0) hp[pix] = 1.0f / (1.0f + expf(-(c + bh2[0])));
  }
}

// -------- conv taps: 3 dilations x 9 taps, 4 ch per lane --------
template <bool EDGE>
__device__ __forceinline__ void do_taps(const ushort* pb,
                                        const float* __restrict__ k1,
                                        const float* __restrict__ k2,
                                        const float* __restrict__ k3, int cg,
                                        int y, int xq, float (&br)[4][4]) {
#pragma unroll
  for (int t = 0; t < 3; ++t) {
    const int dl = (t == 0) ? 1 : ((t == 1) ? 2 : 4);
    const float* kk = (t == 0) ? k1 : ((t == 1) ? k2 : k3);
    float a0 = 0.f, a1 = 0.f, a2 = 0.f, a3 = 0.f;
#pragma unroll
    for (int ky = 0; ky < 3; ++ky) {
#pragma unroll
      for (int kx = 0; kx < 3; ++kx) {
        const int dy = (ky - 1) * dl, dx = (kx - 1) * dl;
        if (EDGE && !(ky == 1 && kx == 1)) {
          if ((unsigned)(y + dy) >= HH) continue;
        }
        const float4 w = *(const float4*)&kk[(ky * 3 + kx) * CH + cg * 4];
        float v0, v1, v2, v3;
        if (ky == 1 && kx == 1) {
          v0 = br[0][0]; v1 = br[0][1]; v2 = br[0][2]; v3 = br[0][3];
        } else {
          ushort4 d4 = *(const ushort4*)(pb + (dy * WW + dx) * CH);
          v0 = b2f(d4.x); v1 = b2f(d4.y); v2 = b2f(d4.z); v3 = b2f(d4.w);
          if (EDGE && (unsigned)(xq + dx) >= WW) {
            v0 = 0.f; v1 = 0.f; v2 = 0.f; v3 = 0.f;
          }
        }
        a0 = fmaf(v0, w.x, a0); a1 = fmaf(v1, w.y, a1);
        a2 = fmaf(v2, w.z, a2); a3 = fmaf(v3, w.w, a3);
      }
    }
    br[t + 1][0] = a0; br[t + 1][1] = a1;
    br[t + 1][2] = a2; br[t + 1][3] = a3;
  }
}

// ---- K2: LIST-DRIVEN dilated convs + LN(256) -> u (fragment-linear tiles) ----
__global__ __launch_bounds__(256) void k_conv_u(
    const ushort* __restrict__ xn, ushort* __restrict__ u,
    const int* __restrict__ lst, const int* __restrict__ cnt, int step,
    const float* __restrict__ k1, const float* __restrict__ k2,
    const float* __restrict__ k3, const float* __restrict__ g2,
    const float* __restrict__ b2) {
  int n = cnt[step * CSTR];
  if (blockIdx.x * 16 >= n) return;
  int wv = threadIdx.x >> 6, l = threadIdx.x & 63;
  int cpx = l >> 4, cg = l & 15;
  int slot = blockIdx.x * 16 + wv * 4 + cpx;
  bool live = slot < n;
  int pix = lst[live ? slot : (n - 1)];
  int b = pix / (HH * WW);
  int rem = pix - b * (HH * WW);
  int y = rem / WW, xq = rem - (rem / WW) * WW;
  const ushort* pb = xn + (size_t)pix * CH + cg * 4;

  float br[4][4];
  {
    ushort4 c4 = *(const ushort4*)pb;
    br[0][0] = b2f(c4.x); br[0][1] = b2f(c4.y);
    br[0][2] = b2f(c4.z); br[0][3] = b2f(c4.w);
  }
  bool interior = (xq >= 4) && (xq <= WW - 5) && (y >= 4) && (y <= HH - 5);
  if (__all(interior))
    do_taps<false>(pb, k1, k2, k3, cg, y, xq, br);
  else
    do_taps<true>(pb, k1, k2, k3, cg, y, xq, br);

  float s = 0.f;
#pragma unroll
  for (int t = 0; t < 4; ++t)
#pragma unroll
    for (int c = 0; c < 4; ++c) s += br[t][c];
  float mean = wsum16(s) * (1.0f / 256.0f);
  float vs = 0.f;
#pragma unroll
  for (int t = 0; t < 4; ++t)
#pragma unroll
    for (int c = 0; c < 4; ++c) {
      float d = br[t][c] - mean;
      vs += d * d;
    }
  float rstd = rsqrtf(wsum16(vs) * (1.0f / 256.0f) + 1e-5f);
  ushort* ub = u + (size_t)blockIdx.x * 4096;
  int lr16 = wv * 4 + cpx;  // slot & 15
  if (live) {
#pragma unroll
    for (int t = 0; t < 4; ++t) {
      float4 g = *(const float4*)&g2[t * CH + cg * 4];
      float4 bb = *(const float4*)&b2[t * CH + cg * 4];
      ushort4 o;
      o.x = f2b((br[t][0] - mean) * rstd * g.x + bb.x);
      o.y = f2b((br[t][1] - mean) * rstd * g.y + bb.y);
      o.z = f2b((br[t][2] - mean) * rstd * g.z + bb.z);
      o.w = f2b((br[t][3] - mean) * rstd * g.w + bb.w);
      int k0 = t * 64 + cg * 4;
      int kt = k0 >> 5, lg = (k0 >> 3) & 3, jj = k0 & 7;
      *(ushort4*)(ub + kt * 512 + (lg * 16 + lr16) * 8 + jj) = o;
    }
  }
}

// ---- K3: LIST-DRIVEN fused MLP + ACT update (R18's proven body) ----
__global__ __launch_bounds__(64) void k_mlp(
    const ushort* __restrict__ u, const int* __restrict__ lst,
    const int* __restrict__ cnt, int step, const ushort* __restrict__ Wp1,
    const ushort* __restrict__ Wp2, const ushort* __restrict__ Wp3,
    const float* __restrict__ bu1, const float* __restrict__ bu2,
    const float* __restrict__ bu3, const float* __restrict__ hp,
    float* __restrict__ xs, float* __restrict__ so, float* __restrict__ halted,
    float* __restrict__ accb, float* __restrict__ pc,
    const int* __restrict__ min_steps) {
  int n = cnt[step * CSTR];
  if (blockIdx.x * 16 >= n) return;
  __shared__ ushort h1s[16 * 136];  // stride 136 (pad 8)
  __shared__ ushort h2s[16 * 72];   // stride 72 (pad 8)
  int l = threadIdx.x;
  int lr = l & 15, lg = l >> 4;
  const f32x4 vzero = {0.0f, 0.0f, 0.0f, 0.0f};

  // ---- prefetch ACT working set (independent of gemms) ----
  int msteps = min_steps[0];
  bool in_halt = (step >= msteps - 1);
  int px = l >> 2, q = l & 3;
  int slotp = blockIdx.x * 16 + px;
  bool livep = slotp < n;
  int p = lst[livep ? slotp : (n - 1)];
  size_t base = (size_t)p * CH + q * 16;
  float4 xv[4], sv[4];
#pragma unroll
  for (int j = 0; j < 4; ++j) xv[j] = *(const float4*)&xs[base + j * 4];
  if (in_halt) {
#pragma unroll
    for (int j = 0; j < 4; ++j) sv[j] = *(const float4*)&so[base + j * 4];
  }
  float hpv = hp[p];
  float accv = accb[p];

  // ---- gemm1: h1 = gelu(u[16,256] @ Wu1[256,128] + bu1) ----
  const ushort* ub = u + (size_t)blockIdx.x * 4096 + l * 8;
  short8 a[8];
#pragma unroll
  for (int kt = 0; kt < 8; ++kt) a[kt] = *(const short8*)(ub + kt * 512);
  f32x4 acc1[8];
#pragma unroll
  for (int nt = 0; nt < 8; ++nt) acc1[nt] = vzero;
#pragma unroll
  for (int kt = 0; kt < 8; ++kt) {
#pragma unroll
    for (int nt = 0; nt < 8; ++nt) {
      short8 b = *(const short8*)(Wp1 + ((kt * 8 + nt) * 64 + l) * 8);
      acc1[nt] = __builtin_amdgcn_mfma_f32_16x16x32_bf16(a[kt], b, acc1[nt], 0, 0, 0);
    }
  }
  ushort* h1w = h1s;
#pragma unroll
  for (int nt = 0; nt < 8; ++nt) {
    float bb = bu1[nt * 16 + lr];
#pragma unroll
    for (int i = 0; i < 4; ++i)
      h1w[(lg * 4 + i) * 136 + nt * 16 + lr] = f2b(gelu_f(acc1[nt][i] + bb));
  }

  // ---- gemm2: h2 = gelu(h1[16,128] @ Wu2[128,64] + bu2) ----
  f32x4 acc2[4];
#pragma unroll
  for (int nt = 0; nt < 4; ++nt) acc2[nt] = vzero;
#pragma unroll
  for (int kt = 0; kt < 4; ++kt) {
    short8 av = *(const short8*)(h1w + lr * 136 + kt * 32 + lg * 8);
#pragma unroll
    for (int nt = 0; nt < 4; ++nt) {
      short8 b = *(const short8*)(Wp2 + ((kt * 4 + nt) * 64 + l) * 8);
      acc2[nt] = __builtin_amdgcn_mfma_f32_16x16x32_bf16(av, b, acc2[nt], 0, 0, 0);
    }
  }
  ushort* h2w = h2s;
#pragma unroll
  for (int nt = 0; nt < 4; ++nt) {
    float bb = bu2[nt * 16 + lr];
#pragma unroll
    for (int i = 0; i < 4; ++i)
      h2w[(lg * 4 + i) * 72 + nt * 16 + lr] = f2b(gelu_f(acc2[nt][i] + bb));
  }

  // ---- gemm3: delta = h2[16,64] @ Wu3[64,64] + bu3 ----
  f32x4 acc3[4];
#pragma unroll
  for (int nt = 0; nt < 4; ++nt) acc3[nt] = vzero;
#pragma unroll
  for (int kt = 0; kt < 2; ++kt) {
    short8 av = *(const short8*)(h2w + lr * 72 + kt * 32 + lg * 8);
#pragma unroll
    for (int nt = 0; nt < 4; ++nt) {
      short8 b = *(const short8*)(Wp3 + ((kt * 4 + nt) * 64 + l) * 8);
      acc3[nt] = __builtin_amdgcn_mfma_f32_16x16x32_bf16(av, b, acc3[nt], 0, 0, 0);
    }
  }
  float* df = (float*)h1w;  // delta fp32 reuses h1 slab
#pragma unroll
  for (int nt = 0; nt < 4; ++nt) {
    float bb = bu3[nt * 16 + lr];
#pragma unroll
    for (int i = 0; i < 4; ++i)
      df[(lg * 4 + i) * 68 + nt * 16 + lr] = acc3[nt][i] + bb;
  }

  // ---- ACT update: lane l -> list slot l>>2, channel quarter l&3 ----
  if (livep) {
    float acc_n = accv + hpv;
    bool should_halt = (acc_n > 0.99f);
    float halt_w = should_halt ? (1.0f - (acc_n - hpv)) : hpv;
#pragma unroll
    for (int j = 0; j < 4; ++j) {
      float4 dv = *(const float4*)&df[px * 68 + q * 16 + j * 4];
      float4 x2 = xv[j];
      x2.x += dv.x; x2.y += dv.y; x2.z += dv.z; x2.w += dv.w;
      *(float4*)&xs[base + j * 4] = x2;
      if (in_halt) {
        float4 s2 = sv[j];
        s2.x += x2.x * halt_w;
        s2.y += x2.y * halt_w;
        s2.z += x2.z * halt_w;
        s2.w += x2.w * halt_w;
        *(float4*)&so[base + j * 4] = s2;
      }
    }
    if (q == 0) {
      if (in_halt) {
        accb[p] = acc_n;
        halted[p] = should_halt ? 1.0f : 0.0f;
      }
      pc[p] += 1.0f;
    }
  }
}

// ---------------- final: distribute remaining mass, pc /= max_steps ----------------
__global__ __launch_bounds__(256) void k_final(
    const float* __restrict__ xs, float* __restrict__ so,
    const float* __restrict__ halted, const float* __restrict__ accb,
    float* __restrict__ pc, const int* __restrict__ max_steps) {
  int wave = threadIdx.x >> 6, lane = threadIdx.x & 63;
  int pix = blockIdx.x * 4 + wave;
  float rem = (halted[pix] == 0.0f) ? (1.0f - accb[pix]) : 0.0f;
  so[(size_t)pix * CH + lane] += xs[(size_t)pix * CH + lane] * rem;
  if (lane == 0) pc[pix] *= 1.0f / (float)max_steps[0];
}

extern "C" void kernel_launch(void* const* d_in, const int* in_sizes, int n_in,
                              void* d_out, int out_size, void* d_ws,
                              size_t ws_size, hipStream_t stream) {
  const float* x   = (const float*)d_in[0];
  const float* g1  = (const float*)d_in[1];
  const float* b1  = (const float*)d_in[2];
  const float* g2  = (const float*)d_in[3];
  const float* b2  = (const float*)d_in[4];
  const float* k1  = (const float*)d_in[5];
  const float* k2  = (const float*)d_in[6];
  const float* k3  = (const float*)d_in[7];
  const float* Wu1 = (const float*)d_in[8];
  const float* bu1 = (const float*)d_in[9];
  const float* Wu2 = (const float*)d_in[10];
  const float* bu2 = (const float*)d_in[11];
  const float* Wu3 = (const float*)d_in[12];
  const float* bu3 = (const float*)d_in[13];
  const float* gh  = (const float*)d_in[14];
  const float* bh  = (const float*)d_in[15];
  const float* Wh1 = (const float*)d_in[16];
  const float* bh1 = (const float*)d_in[17];
  const float* Wh2 = (const float*)d_in[18];
  const float* bh2 = (const float*)d_in[19];
  const int* max_steps = (const int*)d_in[20];
  const int* min_steps = (const int*)d_in[21];

  if (ws_size < (size_t)70000000) return;
  char* ws = (char*)d_ws;
  float*  xs   = (float*)(ws);              // N*64 f32
  ushort* xn   = (ushort*)(ws + 18874368);  // N*64 bf16
  ushort* u    = (ushort*)(ws + 28311552);  // N*256 bf16 (fragment-linear tiles)
  float*  hp   = (float*)(ws + 66060288);   // N f32
  float*  accb = (float*)(ws + 66355200);   // N f32
  ushort* Wp1  = (ushort*)(ws + 66650112);  // 32768 bf16
  ushort* Wp2  = (ushort*)(ws + 66715648);  // 8192 bf16
  ushort* Wp3  = (ushort*)(ws + 66732032);  // 4096 bf16
  int*    idx  = (int*)(ws + 66740224);     // 8 lists x N i32
  int*    cnt  = (int*)(ws + 69394432);     // 9 x CSTR i32 padded counters
  float* so = (float*)d_out;
  float* halted = so + (size_t)NPIX * CH;
  float* pc = halted + NPIX;

  k_wprep_all<<<176, 256, 0, stream>>>(Wu1, Wp1, Wu2, Wp2, Wu3, Wp3);
  k_init<<<19008, 256, 0, stream>>>(x, xs, so, accb, cnt);
  for (int step = 0; step < 8; ++step) {  // max_steps fixed at 8
    int ls = (step == 0) ? 0 : (step - 1);
    k_cln<<<NPIX / 256 + NPIX / 4, 256, 0, stream>>>(
        halted, cnt, idx + (size_t)step * NPIX, step, xs, xn, hp,
        idx + (size_t)ls * NPIX, ls, step == 0 ? 1 : 0, g1, b1, gh, bh, Wh1,
        bh1, Wh2, bh2);
    k_conv_u<<<NPIX / 16, 256, 0, stream>>>(xn, u, idx + (size_t)step * NPIX,
                                            cnt, step, k1, k2, k3, g2, b2);
    k_mlp<<<NPIX / 16, 64, 0, stream>>>(u, idx + (size_t)step * NPIX, cnt, step,
                                        Wp1, Wp2, Wp3, bu1, bu2, bu3, hp, xs,
                                        so, halted, accb, pc, min_steps);
  }
  k_final<<<NPIX / 4, 256, 0, stream>>>(xs, so, halted, accb, pc, max_steps);
}

// Round 23
// 616.286 us; speedup vs baseline: 1.0112x; 1.0112x over previous
//
#include <hip/hip_runtime.h>
#include <hip/hip_bf16.h>

#define NPIX 73728
#define CH 64
#define HH 96
#define WW 96
#define PP 256
#define CSTR 32  // counter stride in ints (128B)

typedef __attribute__((ext_vector_type(8))) short short8;
typedef __attribute__((ext_vector_type(4))) float f32x4;

__device__ __forceinline__ float wsum64(float v) {
#pragma unroll
  for (int off = 32; off > 0; off >>= 1) v += __shfl_xor(v, off, 64);
  return v;
}
__device__ __forceinline__ float wsum16(float v) {
#pragma unroll
  for (int off = 1; off < 16; off <<= 1) v += __shfl_xor(v, off, 64);
  return v;
}
__device__ __forceinline__ float gelu_f(float x) {
  return 0.5f * x * (1.0f + erff(x * 0.70710678118654752f));
}
__device__ __forceinline__ float b2f(ushort u) {
  union { unsigned int i; float f; } c;
  c.i = ((unsigned int)u) << 16;
  return c.f;
}
__device__ __forceinline__ ushort f2b(float f) {
  union { float f; unsigned int i; } c;
  c.f = f;
  unsigned int r = c.i + 0x7fff + ((c.i >> 16) & 1);
  return (ushort)(r >> 16);
}

// ------- init: xs = x, zero outputs/acc, zero padded counters -------
__global__ __launch_bounds__(256) void k_init(const float* __restrict__ x,
                                              float* __restrict__ xs,
                                              float* __restrict__ out,
                                              float* __restrict__ accb,
                                              int* __restrict__ cnt) {
  int i = blockIdx.x * 256 + threadIdx.x;
  if (i < NPIX * CH) xs[i] = x[i];
  if (i < NPIX * 66) out[i] = 0.0f;  // so | halted | pc
  if (i < NPIX) accb[i] = 0.0f;
  if (i < 9 * CSTR) cnt[i] = 0;
}

// ------- weight prep (ALL 3 matrices in one launch) -------
__device__ __forceinline__ void wprep_one(const float* W, ushort* Wp, int t,
                                          int N) {
  int j = t & 7, l = (t >> 3) & 63, tile = t >> 9;
  int NT = N >> 4;
  int kt = tile / NT, nt = tile - kt * NT;
  int k = kt * 32 + ((l >> 4) & 3) * 8 + j;
  int n = nt * 16 + (l & 15);
  Wp[t] = f2b(W[k * N + n]);
}
__global__ __launch_bounds__(256) void k_wprep_all(
    const float* __restrict__ Wu1, ushort* __restrict__ Wp1,
    const float* __restrict__ Wu2, ushort* __restrict__ Wp2,
    const float* __restrict__ Wu3, ushort* __restrict__ Wp3) {
  int t = blockIdx.x * 256 + threadIdx.x;
  if (t < 32768) {
    wprep_one(Wu1, Wp1, t, 128);
  } else if (t < 32768 + 8192) {
    wprep_one(Wu2, Wp2, t - 32768, 64);
  } else if (t < 32768 + 8192 + 4096) {
    wprep_one(Wu3, Wp3, t - 32768 - 8192, 64);
  }
}

// ---- K1: FUSED compact (blocks [0,288)) + list-driven LN/halt (rest) ----
// R21 body: ln half processes all of list[t-1] (xn refresh + hp matvec);
// just-halted pixels' hp is computed but never read again — harmless.
__global__ __launch_bounds__(256) void k_cln(
    const float* __restrict__ halted, int* __restrict__ cnt,
    int* __restrict__ lst_out, int step,
    const float* __restrict__ xs, ushort* __restrict__ xn,
    float* __restrict__ hp, const int* __restrict__ lst_in, int lslot,
    int ident,
    const float* __restrict__ g1, const float* __restrict__ b1,
    const float* __restrict__ gh, const float* __restrict__ bh,
    const float* __restrict__ Wh1, const float* __restrict__ bh1,
    const float* __restrict__ Wh2, const float* __restrict__ bh2) {
  if (blockIdx.x < NPIX / 256) {
    // ---- compaction half ----
    int p = blockIdx.x * 256 + threadIdx.x;
    bool active = (halted[p] == 0.0f);
    unsigned long long mask = __ballot(active);
    int lane = threadIdx.x & 63;
    int cw = __popcll(mask);
    int wbase = 0;
    if (lane == 0 && cw) wbase = atomicAdd(&cnt[step * CSTR], cw);
    wbase = __shfl(wbase, 0, 64);
    if (active) {
      int off = __popcll(mask & ((1ull << lane) - 1ull));
      lst_out[wbase + off] = p;
    }
    return;
  }
  // ---- LN/halt half (R21 body) ----
  int bid = blockIdx.x - NPIX / 256;
  int m = ident ? NPIX : cnt[lslot * CSTR];
  if (bid * 4 >= m) return;
  __shared__ float lnbuf[4][64];
  __shared__ float partials[4][4][64];  // [src wave][pixel][lane]
  int wave = threadIdx.x >> 6, lane = threadIdx.x & 63;
  int slot = bid * 4 + wave;
  bool act = slot < m;
  int sl = act ? slot : m - 1;
  int pix = ident ? sl : lst_in[sl];
  if (act) {
    float x = xs[(size_t)pix * CH + lane];
    float mean = wsum64(x) * (1.0f / 64.0f);
    float d = x - mean;
    float var = wsum64(d * d) * (1.0f / 64.0f);
    float rstd = rsqrtf(var + 1e-5f);
    float nrm = d * rstd;
    xn[(size_t)pix * CH + lane] = f2b(nrm * g1[lane] + b1[lane]);
    lnbuf[wave][lane] = nrm * gh[lane] + bh[lane];
  } else {
    lnbuf[wave][lane] = 0.0f;
  }
  __syncthreads();

  float start = (wave == 0) ? bh1[lane] : 0.0f;
  float p0 = start, p1 = start, p2 = start, p3 = start;
  int i0 = wave * 16;
#pragma unroll 4
  for (int i = i0; i < i0 + 16; ++i) {
    float w = Wh1[i * 64 + lane];
    p0 = fmaf(lnbuf[0][i], w, p0);
    p1 = fmaf(lnbuf[1][i], w, p1);
    p2 = fmaf(lnbuf[2][i], w, p2);
    p3 = fmaf(lnbuf[3][i], w, p3);
  }
  partials[wave][0][lane] = p0;
  partials[wave][1][lane] = p1;
  partials[wave][2][lane] = p2;
  partials[wave][3][lane] = p3;
  __syncthreads();

  if (act) {
    float s = (partials[0][wave][lane] + partials[1][wave][lane]) +
              (partials[2][wave][lane] + partials[3][wave][lane]);
    float acc = gelu_f(s);
    float c = wsum64(acc * Wh2[lane]);
    if (lane == 0) hp[pix] = 1.0f / (1.0f + expf(-(c + bh2[0])));
  }
}

// -------- conv taps: 3 dilations x 9 taps, 4 ch per lane --------
template <bool EDGE>
__device__ __forceinline__ void do_taps(const ushort* pb,
                                        const float* __restrict__ k1,
                                        const float* __restrict__ k2,
                                        const float* __restrict__ k3, int cg,
                                        int y, int xq, float (&br)[4][4]) {
#pragma unroll
  for (int t = 0; t < 3; ++t) {
    const int dl = (t == 0) ? 1 : ((t == 1) ? 2 : 4);
    const float* kk = (t == 0) ? k1 : ((t == 1) ? k2 : k3);
    float a0 = 0.f, a1 = 0.f, a2 = 0.f, a3 = 0.f;
#pragma unroll
    for (int ky = 0; ky < 3; ++ky) {
#pragma unroll
      for (int kx = 0; kx < 3; ++kx) {
        const int dy = (ky - 1) * dl, dx = (kx - 1) * dl;
        if (EDGE && !(ky == 1 && kx == 1)) {
          if ((unsigned)(y + dy) >= HH) continue;
        }
        const float4 w = *(const float4*)&kk[(ky * 3 + kx) * CH + cg * 4];
        float v0, v1, v2, v3;
        if (ky == 1 && kx == 1) {
          v0 = br[0][0]; v1 = br[0][1]; v2 = br[0][2]; v3 = br[0][3];
        } else {
          ushort4 d4 = *(const ushort4*)(pb + (dy * WW + dx) * CH);
          v0 = b2f(d4.x); v1 = b2f(d4.y); v2 = b2f(d4.z); v3 = b2f(d4.w);
          if (EDGE && (unsigned)(xq + dx) >= WW) {
            v0 = 0.f; v1 = 0.f; v2 = 0.f; v3 = 0.f;
          }
        }
        a0 = fmaf(v0, w.x, a0); a1 = fmaf(v1, w.y, a1);
        a2 = fmaf(v2, w.z, a2); a3 = fmaf(v3, w.w, a3);
      }
    }
    br[t + 1][0] = a0; br[t + 1][1] = a1;
    br[t + 1][2] = a2; br[t + 1][3] = a3;
  }
}

// ---- K2: LIST-DRIVEN dilated convs + LN(256) -> u (fragment-linear tiles) ----
__global__ __launch_bounds__(256) void k_conv_u(
    const ushort* __restrict__ xn, ushort* __restrict__ u,
    const int* __restrict__ lst, const int* __restrict__ cnt, int step,
    const float* __restrict__ k1, const float* __restrict__ k2,
    const float* __restrict__ k3, const float* __restrict__ g2,
    const float* __restrict__ b2) {
  int n = cnt[step * CSTR];
  if (blockIdx.x * 16 >= n) return;
  int wv = threadIdx.x >> 6, l = threadIdx.x & 63;
  int cpx = l >> 4, cg = l & 15;
  int slot = blockIdx.x * 16 + wv * 4 + cpx;
  bool live = slot < n;
  int pix = lst[live ? slot : (n - 1)];
  int b = pix / (HH * WW);
  int rem = pix - b * (HH * WW);
  int y = rem / WW, xq = rem - (rem / WW) * WW;
  const ushort* pb = xn + (size_t)pix * CH + cg * 4;

  float br[4][4];
  {
    ushort4 c4 = *(const ushort4*)pb;
    br[0][0] = b2f(c4.x); br[0][1] = b2f(c4.y);
    br[0][2] = b2f(c4.z); br[0][3] = b2f(c4.w);
  }
  bool interior = (xq >= 4) && (xq <= WW - 5) && (y >= 4) && (y <= HH - 5);
  if (__all(interior))
    do_taps<false>(pb, k1, k2, k3, cg, y, xq, br);
  else
    do_taps<true>(pb, k1, k2, k3, cg, y, xq, br);

  float s = 0.f;
#pragma unroll
  for (int t = 0; t < 4; ++t)
#pragma unroll
    for (int c = 0; c < 4; ++c) s += br[t][c];
  float mean = wsum16(s) * (1.0f / 256.0f);
  float vs = 0.f;
#pragma unroll
  for (int t = 0; t < 4; ++t)
#pragma unroll
    for (int c = 0; c < 4; ++c) {
      float d = br[t][c] - mean;
      vs += d * d;
    }
  float rstd = rsqrtf(wsum16(vs) * (1.0f / 256.0f) + 1e-5f);
  ushort* ub = u + (size_t)blockIdx.x * 4096;
  int lr16 = wv * 4 + cpx;  // slot & 15
  if (live) {
#pragma unroll
    for (int t = 0; t < 4; ++t) {
      float4 g = *(const float4*)&g2[t * CH + cg * 4];
      float4 bb = *(const float4*)&b2[t * CH + cg * 4];
      ushort4 o;
      o.x = f2b((br[t][0] - mean) * rstd * g.x + bb.x);
      o.y = f2b((br[t][1] - mean) * rstd * g.y + bb.y);
      o.z = f2b((br[t][2] - mean) * rstd * g.z + bb.z);
      o.w = f2b((br[t][3] - mean) * rstd * g.w + bb.w);
      int k0 = t * 64 + cg * 4;
      int kt = k0 >> 5, lg = (k0 >> 3) & 3, jj = k0 & 7;
      *(ushort4*)(ub + kt * 512 + (lg * 16 + lr16) * 8 + jj) = o;
    }
  }
}

// ---- K3: LIST-DRIVEN fused MLP + ACT update (R18's proven body) ----
__global__ __launch_bounds__(64) void k_mlp(
    const ushort* __restrict__ u, const int* __restrict__ lst,
    const int* __restrict__ cnt, int step, const ushort* __restrict__ Wp1,
    const ushort* __restrict__ Wp2, const ushort* __restrict__ Wp3,
    const float* __restrict__ bu1, const float* __restrict__ bu2,
    const float* __restrict__ bu3, const float* __restrict__ hp,
    float* __restrict__ xs, float* __restrict__ so, float* __restrict__ halted,
    float* __restrict__ accb, float* __restrict__ pc,
    const int* __restrict__ min_steps) {
  int n = cnt[step * CSTR];
  if (blockIdx.x * 16 >= n) return;
  __shared__ ushort h1s[16 * 136];  // stride 136 (pad 8)
  __shared__ ushort h2s[16 * 72];   // stride 72 (pad 8)
  int l = threadIdx.x;
  int lr = l & 15, lg = l >> 4;
  const f32x4 vzero = {0.0f, 0.0f, 0.0f, 0.0f};

  // ---- prefetch ACT working set (independent of gemms) ----
  int msteps = min_steps[0];
  bool in_halt = (step >= msteps - 1);
  int px = l >> 2, q = l & 3;
  int slotp = blockIdx.x * 16 + px;
  bool livep = slotp < n;
  int p = lst[livep ? slotp : (n - 1)];
  size_t base = (size_t)p * CH + q * 16;
  float4 xv[4], sv[4];
#pragma unroll
  for (int j = 0; j < 4; ++j) xv[j] = *(const float4*)&xs[base + j * 4];
  if (in_halt) {
#pragma unroll
    for (int j = 0; j < 4; ++j) sv[j] = *(const float4*)&so[base + j * 4];
  }
  float hpv = hp[p];
  float accv = accb[p];

  // ---- gemm1: h1 = gelu(u[16,256] @ Wu1[256,128] + bu1) ----
  const ushort* ub = u + (size_t)blockIdx.x * 4096 + l * 8;
  short8 a[8];
#pragma unroll
  for (int kt = 0; kt < 8; ++kt) a[kt] = *(const short8*)(ub + kt * 512);
  f32x4 acc1[8];
#pragma unroll
  for (int nt = 0; nt < 8; ++nt) acc1[nt] = vzero;
#pragma unroll
  for (int kt = 0; kt < 8; ++kt) {
#pragma unroll
    for (int nt = 0; nt < 8; ++nt) {
      short8 b = *(const short8*)(Wp1 + ((kt * 8 + nt) * 64 + l) * 8);
      acc1[nt] = __builtin_amdgcn_mfma_f32_16x16x32_bf16(a[kt], b, acc1[nt], 0, 0, 0);
    }
  }
  ushort* h1w = h1s;
#pragma unroll
  for (int nt = 0; nt < 8; ++nt) {
    float bb = bu1[nt * 16 + lr];
#pragma unroll
    for (int i = 0; i < 4; ++i)
      h1w[(lg * 4 + i) * 136 + nt * 16 + lr] = f2b(gelu_f(acc1[nt][i] + bb));
  }

  // ---- gemm2: h2 = gelu(h1[16,128] @ Wu2[128,64] + bu2) ----
  f32x4 acc2[4];
#pragma unroll
  for (int nt = 0; nt < 4; ++nt) acc2[nt] = vzero;
#pragma unroll
  for (int kt = 0; kt < 4; ++kt) {
    short8 av = *(const short8*)(h1w + lr * 136 + kt * 32 + lg * 8);
#pragma unroll
    for (int nt = 0; nt < 4; ++nt) {
      short8 b = *(const short8*)(Wp2 + ((kt * 4 + nt) * 64 + l) * 8);
      acc2[nt] = __builtin_amdgcn_mfma_f32_16x16x32_bf16(av, b, acc2[nt], 0, 0, 0);
    }
  }
  ushort* h2w = h2s;
#pragma unroll
  for (int nt = 0; nt < 4; ++nt) {
    float bb = bu2[nt * 16 + lr];
#pragma unroll
    for (int i = 0; i < 4; ++i)
      h2w[(lg * 4 + i) * 72 + nt * 16 + lr] = f2b(gelu_f(acc2[nt][i] + bb));
  }

  // ---- gemm3: delta = h2[16,64] @ Wu3[64,64] + bu3 ----
  f32x4 acc3[4];
#pragma unroll
  for (int nt = 0; nt < 4; ++nt) acc3[nt] = vzero;
#pragma unroll
  for (int kt = 0; kt < 2; ++kt) {
    short8 av = *(const short8*)(h2w + lr * 72 + kt * 32 + lg * 8);
#pragma unroll
    for (int nt = 0; nt < 4; ++nt) {
      short8 b = *(const short8*)(Wp3 + ((kt * 4 + nt) * 64 + l) * 8);
      acc3[nt] = __builtin_amdgcn_mfma_f32_16x16x32_bf16(av, b, acc3[nt], 0, 0, 0);
    }
  }
  float* df = (float*)h1w;  // delta fp32 reuses h1 slab
#pragma unroll
  for (int nt = 0; nt < 4; ++nt) {
    float bb = bu3[nt * 16 + lr];
#pragma unroll
    for (int i = 0; i < 4; ++i)
      df[(lg * 4 + i) * 68 + nt * 16 + lr] = acc3[nt][i] + bb;
  }

  // ---- ACT update: lane l -> list slot l>>2, channel quarter l&3 ----
  if (livep) {
    float acc_n = accv + hpv;
    bool should_halt = (acc_n > 0.99f);
    float halt_w = should_halt ? (1.0f - (acc_n - hpv)) : hpv;
#pragma unroll
    for (int j = 0; j < 4; ++j) {
      float4 dv = *(const float4*)&df[px * 68 + q * 16 + j * 4];
      float4 x2 = xv[j];
      x2.x += dv.x; x2.y += dv.y; x2.z += dv.z; x2.w += dv.w;
      *(float4*)&xs[base + j * 4] = x2;
      if (in_halt) {
        float4 s2 = sv[j];
        s2.x += x2.x * halt_w;
        s2.y += x2.y * halt_w;
        s2.z += x2.z * halt_w;
        s2.w += x2.w * halt_w;
        *(float4*)&so[base + j * 4] = s2;
      }
    }
    if (q == 0) {
      if (in_halt) {
        accb[p] = acc_n;
        halted[p] = should_halt ? 1.0f : 0.0f;
      }
      pc[p] += 1.0f;
    }
  }
}

// ---------------- final: distribute remaining mass, pc /= max_steps ----------------
__global__ __launch_bounds__(256) void k_final(
    const float* __restrict__ xs, float* __restrict__ so,
    const float* __restrict__ halted, const float* __restrict__ accb,
    float* __restrict__ pc, const int* __restrict__ max_steps) {
  int wave = threadIdx.x >> 6, lane = threadIdx.x & 63;
  int pix = blockIdx.x * 4 + wave;
  float rem = (halted[pix] == 0.0f) ? (1.0f - accb[pix]) : 0.0f;
  so[(size_t)pix * CH + lane] += xs[(size_t)pix * CH + lane] * rem;
  if (lane == 0) pc[pix] *= 1.0f / (float)max_steps[0];
}

extern "C" void kernel_launch(void* const* d_in, const int* in_sizes, int n_in,
                              void* d_out, int out_size, void* d_ws,
                              size_t ws_size, hipStream_t stream) {
  const float* x   = (const float*)d_in[0];
  const float* g1  = (const float*)d_in[1];
  const float* b1  = (const float*)d_in[2];
  const float* g2  = (const float*)d_in[3];
  const float* b2  = (const float*)d_in[4];
  const float* k1  = (const float*)d_in[5];
  const float* k2  = (const float*)d_in[6];
  const float* k3  = (const float*)d_in[7];
  const float* Wu1 = (const float*)d_in[8];
  const float* bu1 = (const float*)d_in[9];
  const float* Wu2 = (const float*)d_in[10];
  const float* bu2 = (const float*)d_in[11];
  const float* Wu3 = (const float*)d_in[12];
  const float* bu3 = (const float*)d_in[13];
  const float* gh  = (const float*)d_in[14];
  const float* bh  = (const float*)d_in[15];
  const float* Wh1 = (const float*)d_in[16];
  const float* bh1 = (const float*)d_in[17];
  const float* Wh2 = (const float*)d_in[18];
  const float* bh2 = (const float*)d_in[19];
  const int* max_steps = (const int*)d_in[20];
  const int* min_steps = (const int*)d_in[21];

  if (ws_size < (size_t)70000000) return;
  char* ws = (char*)d_ws;
  float*  xs   = (float*)(ws);              // N*64 f32
  ushort* xn   = (ushort*)(ws + 18874368);  // N*64 bf16
  ushort* u    = (ushort*)(ws + 28311552);  // N*256 bf16 (fragment-linear tiles)
  float*  hp   = (float*)(ws + 66060288);   // N f32
  float*  accb = (float*)(ws + 66355200);   // N f32
  ushort* Wp1  = (ushort*)(ws + 66650112);  // 32768 bf16
  ushort* Wp2  = (ushort*)(ws + 66715648);  // 8192 bf16
  ushort* Wp3  = (ushort*)(ws + 66732032);  // 4096 bf16
  int*    idx  = (int*)(ws + 66740224);     // 8 lists x N i32
  int*    cnt  = (int*)(ws + 69394432);     // 9 x CSTR i32 padded counters
  float* so = (float*)d_out;
  float* halted = so + (size_t)NPIX * CH;
  float* pc = halted + NPIX;

  k_wprep_all<<<176, 256, 0, stream>>>(Wu1, Wp1, Wu2, Wp2, Wu3, Wp3);
  k_init<<<19008, 256, 0, stream>>>(x, xs, so, accb, cnt);
  for (int step = 0; step < 8; ++step) {  // max_steps fixed at 8
    int ls = (step == 0) ? 0 : (step - 1);
    k_cln<<<NPIX / 256 + NPIX / 4, 256, 0, stream>>>(
        halted, cnt, idx + (size_t)step * NPIX, step, xs, xn, hp,
        idx + (size_t)ls * NPIX, ls, step == 0 ? 1 : 0, g1, b1, gh, bh, Wh1,
        bh1, Wh2, bh2);
    k_conv_u<<<NPIX / 16, 256, 0, stream>>>(xn, u, idx + (size_t)step * NPIX,
                                            cnt, step, k1, k2, k3, g2, b2);
    k_mlp<<<NPIX / 16, 64, 0, stream>>>(u, idx + (size_t)step * NPIX, cnt, step,
                                        Wp1, Wp2, Wp3, bu1, bu2, bu3, hp, xs,
                                        so, halted, accb, pc, min_steps);
  }
  k_final<<<NPIX / 4, 256, 0, stream>>>(xs, so, halted, accb, pc, max_steps);
}